// Round 4
// baseline (1212.262 us; speedup 1.0000x reference)
//
#include <hip/hip_runtime.h>
#include <cfloat>

#define D 256
#define NE 1024
#define NROWS 65536
#define BETA 0.25f

// ws layout (bytes):
//   [0]              int count
//   [64]             int list[65536]            (256 KB)
//   [64+256K]        float w2[1024]             (4 KB)
//   [64+256K+4K]     float z2[65536]            (256 KB)

__global__ __launch_bounds__(256) void k0_z2(const float* __restrict__ z,
                                             float* __restrict__ z2) {
  const int wid = threadIdx.x >> 6, lane = threadIdx.x & 63;
  const int row = blockIdx.x * 4 + wid;
  const float4 v =
      *reinterpret_cast<const float4*>(z + (size_t)row * D + lane * 4);
  double s = (double)v.x * v.x + (double)v.y * v.y + (double)v.z * v.z +
             (double)v.w * v.w;
#pragma unroll
  for (int off = 32; off > 0; off >>= 1) s += __shfl_down(s, off, 64);
  if (lane == 0) z2[row] = (float)s;
}

__global__ __launch_bounds__(64) void k1_w2(const float* __restrict__ w,
                                            float* __restrict__ w2,
                                            int* __restrict__ count) {
  const int j = blockIdx.x;
  const int lane = threadIdx.x;
  const float4 v =
      *reinterpret_cast<const float4*>(w + (size_t)j * D + lane * 4);
  double s = (double)v.x * v.x + (double)v.y * v.y + (double)v.z * v.z +
             (double)v.w * v.w;
#pragma unroll
  for (int off = 32; off > 0; off >>= 1) s += __shfl_down(s, off, 64);
  if (lane == 0) {
    w2[j] = (float)s;
    if (j == 0) *count = 0;
  }
}

// Fused GEMM + quantized-f32 argmin (replicates reference rounding chain:
// dist = fl32(fl32(z2 - 2*fl32(zw)) + w2), first-index tie-break).
__global__ __launch_bounds__(256) void k2_argmin(
    const float* __restrict__ z, const float* __restrict__ w,
    const float* __restrict__ w2, const float* __restrict__ z2,
    float* __restrict__ idxf, int* __restrict__ count,
    int* __restrict__ list) {
  __shared__ float As[32][68];
  __shared__ float Bs[32][132];
  __shared__ float lm1[64][16];
  __shared__ float lm2[64][16];
  __shared__ int li1[64][16];

  const int tid = threadIdx.x;
  const int r0 = blockIdx.x * 64;
  const int trow = tid >> 4;
  const int tcol = tid & 15;

  float z2v[4];
#pragma unroll
  for (int i = 0; i < 4; ++i) z2v[i] = z2[r0 + trow * 4 + i];

  float m1[4], m2[4];
  int i1[4];
#pragma unroll
  for (int i = 0; i < 4; ++i) { m1[i] = FLT_MAX; m2[i] = FLT_MAX; i1[i] = 0; }

  for (int cb = 0; cb < 8; ++cb) {
    float acc[4][8];
#pragma unroll
    for (int i = 0; i < 4; ++i)
#pragma unroll
      for (int j = 0; j < 8; ++j) acc[i][j] = 0.0f;

    for (int kb = 0; kb < 8; ++kb) {
      __syncthreads();
#pragma unroll
      for (int it = 0; it < 2; ++it) {
        const int f = tid + it * 256;
        const int row = f >> 3;
        const int kq = f & 7;
        const float4 v = *reinterpret_cast<const float4*>(
            z + (size_t)(r0 + row) * D + kb * 32 + kq * 4);
        As[kq * 4 + 0][row] = v.x;
        As[kq * 4 + 1][row] = v.y;
        As[kq * 4 + 2][row] = v.z;
        As[kq * 4 + 3][row] = v.w;
      }
#pragma unroll
      for (int it = 0; it < 4; ++it) {
        const int g = tid + it * 256;
        const int c = g >> 3;
        const int kq = g & 7;
        const float4 v = *reinterpret_cast<const float4*>(
            w + (size_t)(cb * 128 + c) * D + kb * 32 + kq * 4);
        Bs[kq * 4 + 0][c] = v.x;
        Bs[kq * 4 + 1][c] = v.y;
        Bs[kq * 4 + 2][c] = v.z;
        Bs[kq * 4 + 3][c] = v.w;
      }
      __syncthreads();
#pragma unroll
      for (int k = 0; k < 32; ++k) {
        const float4 a = *reinterpret_cast<const float4*>(&As[k][trow * 4]);
        const float4 b0 = *reinterpret_cast<const float4*>(&Bs[k][tcol * 8]);
        const float4 b1 =
            *reinterpret_cast<const float4*>(&Bs[k][tcol * 8 + 4]);
        const float av[4] = {a.x, a.y, a.z, a.w};
        const float bv[8] = {b0.x, b0.y, b0.z, b0.w, b1.x, b1.y, b1.z, b1.w};
#pragma unroll
        for (int i = 0; i < 4; ++i)
#pragma unroll
          for (int j = 0; j < 8; ++j)
            acc[i][j] = fmaf(av[i], bv[j], acc[i][j]);
      }
    }
    // quantized reference-rounding scores
    const int cbase = cb * 128 + tcol * 8;
#pragma unroll
    for (int j = 0; j < 8; ++j) {
      const float w2c = w2[cbase + j];
      const int c = cbase + j;
#pragma unroll
      for (int i = 0; i < 4; ++i) {
        const float t2 = z2v[i] - 2.0f * acc[i][j];  // fl32(z2 - 2*zw)
        const float sc = t2 + w2c;                    // fl32(.. + w2)
        if (sc < m1[i]) {
          m2[i] = m1[i];
          m1[i] = sc;
          i1[i] = c;
        } else if (sc < m2[i]) {
          m2[i] = sc;
        }
      }
    }
  }

  __syncthreads();
#pragma unroll
  for (int i = 0; i < 4; ++i) {
    lm1[trow * 4 + i][tcol] = m1[i];
    lm2[trow * 4 + i][tcol] = m2[i];
    li1[trow * 4 + i][tcol] = i1[i];
  }
  __syncthreads();
  if (tid < 64) {
    float M1 = FLT_MAX, M2 = FLT_MAX;
    int I1 = 0x7fffffff;
    for (int c = 0; c < 16; ++c) {
      const float a1 = lm1[tid][c];
      const float a2 = lm2[tid][c];
      const int ai = li1[tid][c];
      if (a1 < M1 || (a1 == M1 && ai < I1)) {
        M2 = fminf(M1, a2);
        M1 = a1;
        I1 = ai;
      } else {
        M2 = fminf(M2, a1);
      }
    }
    const int row = r0 + tid;
    idxf[row] = (float)I1;
    // rescue any row whose top-2 quantized scores are within ~3 ulp(256)
    if (M2 - M1 < 1e-4f) {
      const int pos = atomicAdd(count, 1);
      list[pos] = row;
    }
  }
}

// Rescue: recompute zw in f64, then apply the EXACT f32 rounding chain and
// first-index-tie argmin. Resolves bucket membership exactly.
__global__ __launch_bounds__(256) void k3_rescue(
    const float* __restrict__ z, const float* __restrict__ w,
    const float* __restrict__ w2, const float* __restrict__ z2,
    float* __restrict__ idxf, const int* __restrict__ count,
    const int* __restrict__ list) {
  __shared__ float zs[D];
  __shared__ float rs[256];
  __shared__ int ri[256];
  const int t = threadIdx.x;
  const int cnt = *count;
  for (int i = blockIdx.x; i < cnt; i += gridDim.x) {
    const int row = list[i];
    __syncthreads();
    zs[t] = z[(size_t)row * D + t];
    __syncthreads();
    const float z2r = z2[row];
    float best = FLT_MAX;
    int bi = 0x7fffffff;
    for (int q = 0; q < 4; ++q) {
      const int c = q * 256 + t;
      const float* wr = w + (size_t)c * D;
      double s = 0.0;
      for (int d = 0; d < D; ++d) s = fma((double)zs[d], (double)wr[d], s);
      const float b32 = (float)s;          // fl32(zw), near-exact
      const float t2 = z2r - 2.0f * b32;   // fl32
      const float dist = t2 + w2[c];       // fl32
      if (dist < best) {                   // strict < keeps first index
        best = dist;
        bi = c;
      }
    }
    rs[t] = best;
    ri[t] = bi;
    __syncthreads();
    for (int off = 128; off > 0; off >>= 1) {
      if (t < off) {
        if (rs[t + off] < rs[t] ||
            (rs[t + off] == rs[t] && ri[t + off] < ri[t])) {
          rs[t] = rs[t + off];
          ri[t] = ri[t + off];
        }
      }
      __syncthreads();
    }
    if (t == 0) idxf[row] = (float)ri[0];
  }
}

__global__ __launch_bounds__(256) void k4_out(
    const float* __restrict__ z, const float* __restrict__ w,
    const float* __restrict__ idxf, float* __restrict__ zq,
    float* __restrict__ loss) {
  const int wid = threadIdx.x >> 6;
  const int lane = threadIdx.x & 63;
  const int row = blockIdx.x * 4 + wid;
  const int idx = (int)idxf[row];
  const float4 zv =
      *reinterpret_cast<const float4*>(z + (size_t)row * D + lane * 4);
  const float4 qv =
      *reinterpret_cast<const float4*>(w + (size_t)idx * D + lane * 4);
  const float dx = qv.x - zv.x, dy = qv.y - zv.y;
  const float dz2 = qv.z - zv.z, dw = qv.w - zv.w;
  float4 o;
  o.x = zv.x + dx;
  o.y = zv.y + dy;
  o.z = zv.z + dz2;
  o.w = zv.w + dw;
  *reinterpret_cast<float4*>(zq + (size_t)row * D + lane * 4) = o;
  float d2 = dx * dx + dy * dy + dz2 * dz2 + dw * dw;
#pragma unroll
  for (int off = 32; off > 0; off >>= 1) d2 += __shfl_down(d2, off, 64);
  if (lane == 0) {
    const float m = d2 * (1.0f / 256.0f);
    loss[row] = m + BETA * m;
  }
}

extern "C" void kernel_launch(void* const* d_in, const int* in_sizes, int n_in,
                              void* d_out, int out_size, void* d_ws,
                              size_t ws_size, hipStream_t stream) {
  const float* z = (const float*)d_in[0];
  const float* w = (const float*)d_in[1];
  float* out = (float*)d_out;
  float* zq = out;
  float* loss = out + (size_t)NROWS * D;
  float* idxf = loss + NROWS;

  char* ws = (char*)d_ws;
  int* count = (int*)(ws);
  int* list = (int*)(ws + 64);
  float* w2 = (float*)(ws + 64 + (size_t)NROWS * 4);
  float* z2 = (float*)(ws + 64 + (size_t)NROWS * 4 + 4096);

  k0_z2<<<NROWS / 4, 256, 0, stream>>>(z, z2);
  k1_w2<<<NE, 64, 0, stream>>>(w, w2, count);
  k2_argmin<<<NROWS / 64, 256, 0, stream>>>(z, w, w2, z2, idxf, count, list);
  k3_rescue<<<64, 256, 0, stream>>>(z, w, w2, z2, idxf, count, list);
  k4_out<<<NROWS / 4, 256, 0, stream>>>(z, w, idxf, zq, loss);
}

// Round 6
// 947.933 us; speedup vs baseline: 1.2788x; 1.2788x over previous
//
#include <hip/hip_runtime.h>
#include <cfloat>

#define D 256
#define NE 1024
#define NROWS 65536
#define BETA 0.25f
#define RESCUE_THR 1e-4f

// ws layout (bytes):
//   [0]              int count
//   [64]             int list[65536]            (256 KB)
//   [64+256K]        float w2[1024]             (4 KB)
//   [64+256K+4K]     float z2[65536]            (256 KB)

__global__ __launch_bounds__(256) void k0_z2(const float* __restrict__ z,
                                             float* __restrict__ z2) {
  const int wid = threadIdx.x >> 6, lane = threadIdx.x & 63;
  const int row = blockIdx.x * 4 + wid;
  const float4 v =
      *reinterpret_cast<const float4*>(z + (size_t)row * D + lane * 4);
  double s = (double)v.x * v.x + (double)v.y * v.y + (double)v.z * v.z +
             (double)v.w * v.w;
#pragma unroll
  for (int off = 32; off > 0; off >>= 1) s += __shfl_down(s, off, 64);
  if (lane == 0) z2[row] = (float)s;
}

__global__ __launch_bounds__(64) void k1_w2(const float* __restrict__ w,
                                            float* __restrict__ w2,
                                            int* __restrict__ count) {
  const int j = blockIdx.x;
  const int lane = threadIdx.x;
  const float4 v =
      *reinterpret_cast<const float4*>(w + (size_t)j * D + lane * 4);
  double s = (double)v.x * v.x + (double)v.y * v.y + (double)v.z * v.z +
             (double)v.w * v.w;
#pragma unroll
  for (int off = 32; off > 0; off >>= 1) s += __shfl_down(s, off, 64);
  if (lane == 0) {
    w2[j] = (float)s;
    if (j == 0) *count = 0;
  }
}

// Fused GEMM + quantized-f32 argmin. 128 rows x 1024 codes per block,
// 8x8 micro-tile (256 threads as 16x16). Chain: fl32(fl32(z2-2*fl32(zw))+w2).
__global__ __launch_bounds__(256) void k2_argmin(
    const float* __restrict__ z, const float* __restrict__ w,
    const float* __restrict__ w2, const float* __restrict__ z2,
    float* __restrict__ idxf, int* __restrict__ count,
    int* __restrict__ list) {
  __shared__ float As[32][132];  // [k][row], 16.9 KB
  __shared__ float Bs[32][132];  // [k][code]

  const int tid = threadIdx.x;
  const int r0 = blockIdx.x * 128;
  const int trow = tid >> 4;  // 0..15 -> rows trow*8..+7
  const int tcol = tid & 15;  // 0..15 -> codes tcol*8..+7

  float z2v[8];
#pragma unroll
  for (int i = 0; i < 8; ++i) z2v[i] = z2[r0 + trow * 8 + i];

  float m1[8], m2[8];
  int i1[8];
#pragma unroll
  for (int i = 0; i < 8; ++i) {
    m1[i] = FLT_MAX;
    m2[i] = FLT_MAX;
    i1[i] = 0x7fffffff;
  }

  for (int cb = 0; cb < 8; ++cb) {
    float acc[8][8];
#pragma unroll
    for (int i = 0; i < 8; ++i)
#pragma unroll
      for (int j = 0; j < 8; ++j) acc[i][j] = 0.0f;

    for (int kb = 0; kb < 8; ++kb) {
      __syncthreads();
#pragma unroll
      for (int it = 0; it < 4; ++it) {
        const int f = tid + it * 256;
        const int row = f >> 3;
        const int kq = f & 7;
        const float4 v = *reinterpret_cast<const float4*>(
            z + (size_t)(r0 + row) * D + kb * 32 + kq * 4);
        As[kq * 4 + 0][row] = v.x;
        As[kq * 4 + 1][row] = v.y;
        As[kq * 4 + 2][row] = v.z;
        As[kq * 4 + 3][row] = v.w;
      }
#pragma unroll
      for (int it = 0; it < 4; ++it) {
        const int f = tid + it * 256;
        const int c = f >> 3;
        const int kq = f & 7;
        const float4 v = *reinterpret_cast<const float4*>(
            w + (size_t)(cb * 128 + c) * D + kb * 32 + kq * 4);
        Bs[kq * 4 + 0][c] = v.x;
        Bs[kq * 4 + 1][c] = v.y;
        Bs[kq * 4 + 2][c] = v.z;
        Bs[kq * 4 + 3][c] = v.w;
      }
      __syncthreads();
#pragma unroll 4
      for (int k = 0; k < 32; ++k) {
        const float4 a0 = *reinterpret_cast<const float4*>(&As[k][trow * 8]);
        const float4 a1 =
            *reinterpret_cast<const float4*>(&As[k][trow * 8 + 4]);
        const float4 b0 = *reinterpret_cast<const float4*>(&Bs[k][tcol * 8]);
        const float4 b1 =
            *reinterpret_cast<const float4*>(&Bs[k][tcol * 8 + 4]);
        const float av[8] = {a0.x, a0.y, a0.z, a0.w, a1.x, a1.y, a1.z, a1.w};
        const float bv[8] = {b0.x, b0.y, b0.z, b0.w, b1.x, b1.y, b1.z, b1.w};
#pragma unroll
        for (int i = 0; i < 8; ++i)
#pragma unroll
          for (int j = 0; j < 8; ++j)
            acc[i][j] = fmaf(av[i], bv[j], acc[i][j]);
      }
    }
    const int cbase = cb * 128 + tcol * 8;
#pragma unroll
    for (int j = 0; j < 8; ++j) {
      const float w2c = w2[cbase + j];
      const int c = cbase + j;
#pragma unroll
      for (int i = 0; i < 8; ++i) {
        const float t2 = z2v[i] - 2.0f * acc[i][j];  // fl32(z2 - 2*fl32(zw))
        const float sc = t2 + w2c;                    // fl32(.. + w2)
        if (sc < m1[i]) {
          m2[i] = m1[i];
          m1[i] = sc;
          i1[i] = c;
        } else if (sc < m2[i]) {
          m2[i] = sc;
        }
      }
    }
  }

  // Reduction: reuse As/Bs LDS. 128 rows x 16 cols.
  float* RM1 = &As[0][0];         // 2048 floats
  float* RM2 = &As[0][0] + 2048;  // 2048 floats (As holds 4224)
  int* RI1 = (int*)&Bs[0][0];     // 2048 ints
  __syncthreads();
#pragma unroll
  for (int i = 0; i < 8; ++i) {
    const int off = (trow * 8 + i) * 16 + tcol;
    RM1[off] = m1[i];
    RM2[off] = m2[i];
    RI1[off] = i1[i];
  }
  __syncthreads();
  if (tid < 128) {
    float M1 = FLT_MAX, M2 = FLT_MAX;
    int I1 = 0x7fffffff;
    for (int c = 0; c < 16; ++c) {
      const float a1 = RM1[tid * 16 + c];
      const float a2 = RM2[tid * 16 + c];
      const int ai = RI1[tid * 16 + c];
      if (a1 < M1 || (a1 == M1 && ai < I1)) {
        M2 = fminf(M1, a2);
        M1 = a1;
        I1 = ai;
      } else {
        M2 = fminf(M2, a1);
      }
    }
    const int row = r0 + tid;
    idxf[row] = (float)I1;
    if (M2 - M1 < RESCUE_THR) {
      const int pos = atomicAdd(count, 1);
      list[pos] = row;
    }
  }
}

// Rescue: tiled gathered f64 re-scan. 64 rescue rows x 1024 codes per tile,
// grid-strided. Exact f32 rounding chain on near-exact f64 zw.
__global__ __launch_bounds__(256) void k3_rescue(
    const float* __restrict__ z, const float* __restrict__ w,
    const float* __restrict__ w2, const float* __restrict__ z2,
    float* __restrict__ idxf, const int* __restrict__ count,
    const int* __restrict__ list) {
  __shared__ float As[32][68];   // [k][row] gathered z, 8.7 KB
  __shared__ float Bs[32][132];  // [k][code]
  __shared__ int rlist[64];
  __shared__ float z2s[64];

  const int tid = threadIdx.x;
  const int trow = tid >> 4;  // 0..15 -> rows trow*4..+3
  const int tcol = tid & 15;  // 0..15 -> codes tcol*8..+7
  const int cnt = *count;
  const int tiles = (cnt + 63) >> 6;

  for (int t = blockIdx.x; t < tiles; t += gridDim.x) {
    __syncthreads();  // protect previous tile's reduction reads
    if (tid < 64) {
      const int g = t * 64 + tid;
      const int r = (g < cnt) ? list[g] : 0;
      rlist[tid] = r;
      z2s[tid] = z2[r];
    }
    __syncthreads();

    float rm[4];
    int ri[4];
#pragma unroll
    for (int i = 0; i < 4; ++i) {
      rm[i] = FLT_MAX;
      ri[i] = 0x7fffffff;
    }

    for (int cb = 0; cb < 8; ++cb) {
      double acc[4][8];
#pragma unroll
      for (int i = 0; i < 4; ++i)
#pragma unroll
        for (int j = 0; j < 8; ++j) acc[i][j] = 0.0;

      for (int kb = 0; kb < 8; ++kb) {
        __syncthreads();
#pragma unroll
        for (int it = 0; it < 2; ++it) {
          const int f = tid + it * 256;
          const int row = f >> 3;
          const int kq = f & 7;
          const float4 v = *reinterpret_cast<const float4*>(
              z + (size_t)rlist[row] * D + kb * 32 + kq * 4);
          As[kq * 4 + 0][row] = v.x;
          As[kq * 4 + 1][row] = v.y;
          As[kq * 4 + 2][row] = v.z;
          As[kq * 4 + 3][row] = v.w;
        }
#pragma unroll
        for (int it = 0; it < 4; ++it) {
          const int f = tid + it * 256;
          const int c = f >> 3;
          const int kq = f & 7;
          const float4 v = *reinterpret_cast<const float4*>(
              w + (size_t)(cb * 128 + c) * D + kb * 32 + kq * 4);
          Bs[kq * 4 + 0][c] = v.x;
          Bs[kq * 4 + 1][c] = v.y;
          Bs[kq * 4 + 2][c] = v.z;
          Bs[kq * 4 + 3][c] = v.w;
        }
        __syncthreads();
#pragma unroll 4
        for (int k = 0; k < 32; ++k) {
          const float4 a = *reinterpret_cast<const float4*>(&As[k][trow * 4]);
          const float4 b0 =
              *reinterpret_cast<const float4*>(&Bs[k][tcol * 8]);
          const float4 b1 =
              *reinterpret_cast<const float4*>(&Bs[k][tcol * 8 + 4]);
          const double av[4] = {(double)a.x, (double)a.y, (double)a.z,
                                (double)a.w};
          const double bv[8] = {(double)b0.x, (double)b0.y, (double)b0.z,
                                (double)b0.w, (double)b1.x, (double)b1.y,
                                (double)b1.z, (double)b1.w};
#pragma unroll
          for (int i = 0; i < 4; ++i)
#pragma unroll
            for (int j = 0; j < 8; ++j)
              acc[i][j] = fma(av[i], bv[j], acc[i][j]);
        }
      }
      const int cbase = cb * 128 + tcol * 8;
#pragma unroll
      for (int j = 0; j < 8; ++j) {
        const float w2c = w2[cbase + j];
        const int c = cbase + j;
#pragma unroll
        for (int i = 0; i < 4; ++i) {
          const float b32 = (float)acc[i][j];        // fl32(zw) exact
          const float t2 = z2s[trow * 4 + i] - 2.0f * b32;
          const float dist = t2 + w2c;
          if (dist < rm[i]) {  // strict <: first index wins (codes ascend)
            rm[i] = dist;
            ri[i] = c;
          }
        }
      }
    }

    float* RM1 = &As[0][0];      // 1024 floats (As holds 2176)
    int* RI1 = (int*)&Bs[0][0];  // 1024 ints
    __syncthreads();
#pragma unroll
    for (int i = 0; i < 4; ++i) {
      const int off = (trow * 4 + i) * 16 + tcol;
      RM1[off] = rm[i];
      RI1[off] = ri[i];
    }
    __syncthreads();
    if (tid < 64) {
      float M1 = FLT_MAX;
      int I1 = 0x7fffffff;
      for (int c = 0; c < 16; ++c) {
        const float a1 = RM1[tid * 16 + c];
        const int ai = RI1[tid * 16 + c];
        if (a1 < M1 || (a1 == M1 && ai < I1)) {
          M1 = a1;
          I1 = ai;
        }
      }
      if (t * 64 + tid < cnt) idxf[rlist[tid]] = (float)I1;
    }
  }
}

__global__ __launch_bounds__(256) void k4_out(
    const float* __restrict__ z, const float* __restrict__ w,
    const float* __restrict__ idxf, float* __restrict__ zq,
    float* __restrict__ loss) {
  const int wid = threadIdx.x >> 6;
  const int lane = threadIdx.x & 63;
  const int row = blockIdx.x * 4 + wid;
  const int idx = (int)idxf[row];
  const float4 zv =
      *reinterpret_cast<const float4*>(z + (size_t)row * D + lane * 4);
  const float4 qv =
      *reinterpret_cast<const float4*>(w + (size_t)idx * D + lane * 4);
  const float dx = qv.x - zv.x, dy = qv.y - zv.y;
  const float dz2 = qv.z - zv.z, dw = qv.w - zv.w;
  float4 o;
  o.x = zv.x + dx;
  o.y = zv.y + dy;
  o.z = zv.z + dz2;
  o.w = zv.w + dw;
  *reinterpret_cast<float4*>(zq + (size_t)row * D + lane * 4) = o;
  float d2 = dx * dx + dy * dy + dz2 * dz2 + dw * dw;
#pragma unroll
  for (int off = 32; off > 0; off >>= 1) d2 += __shfl_down(d2, off, 64);
  if (lane == 0) {
    const float m = d2 * (1.0f / 256.0f);
    loss[row] = m + BETA * m;
  }
}

extern "C" void kernel_launch(void* const* d_in, const int* in_sizes, int n_in,
                              void* d_out, int out_size, void* d_ws,
                              size_t ws_size, hipStream_t stream) {
  const float* z = (const float*)d_in[0];
  const float* w = (const float*)d_in[1];
  float* out = (float*)d_out;
  float* zq = out;
  float* loss = out + (size_t)NROWS * D;
  float* idxf = loss + NROWS;

  char* ws = (char*)d_ws;
  int* count = (int*)(ws);
  int* list = (int*)(ws + 64);
  float* w2 = (float*)(ws + 64 + (size_t)NROWS * 4);
  float* z2 = (float*)(ws + 64 + (size_t)NROWS * 4 + 4096);

  k0_z2<<<NROWS / 4, 256, 0, stream>>>(z, z2);
  k1_w2<<<NE, 64, 0, stream>>>(w, w2, count);
  k2_argmin<<<NROWS / 128, 256, 0, stream>>>(z, w, w2, z2, idxf, count, list);
  k3_rescue<<<256, 256, 0, stream>>>(z, w, w2, z2, idxf, count, list);
  k4_out<<<NROWS / 4, 256, 0, stream>>>(z, w, idxf, zq, loss);
}